// Round 3
// baseline (776.727 us; speedup 1.0000x reference)
//
#include <hip/hip_runtime.h>
#include <stdint.h>

#define TOKENS 8192
#define HIDDEN 2048
#define INTER  5632

typedef _Float16 f16x8 __attribute__((ext_vector_type(8)));
typedef _Float16 f16x2 __attribute__((ext_vector_type(2)));
typedef float    f32x4 __attribute__((ext_vector_type(4)));
typedef unsigned int uint;

// async global->LDS, 16B per lane. LDS dest = wave-uniform base + lane*16.
__device__ __forceinline__ void async_copy16(const void* g, void* l) {
  __builtin_amdgcn_global_load_lds(
      (const __attribute__((address_space(1))) uint*)g,
      (__attribute__((address_space(3))) uint*)l, 16, 0, 0);
}

// ---- int4 -> f16x8 in-register dequant -------------------------------------
// Word w holds nibbles for k=0..7 (GPTQ row-pack). Extraction yields vector
// k-order (k0,k4,k1,k5,k2,k6,k3,k7); A staging (xs, hs) uses the SAME perm,
// so the MFMA dot product is unchanged (bijective k relabeling).
// Math: (q|0x6400) as f16 == 1024+q exactly; minus (1025+z) is exact
// (Sterbenz, both in [1024,2048)); result (q-z-1) * s with one rounding.
union U8 { uint u[4]; f16x8 v; };
__device__ __forceinline__ f16x8 dq8(uint w, uint sd, uint zd) {
  const f16x2 s = __builtin_bit_cast(f16x2, sd);
  const f16x2 z = __builtin_bit_cast(f16x2, zd);
  U8 r;
  uint t0 = (w & 0x000F000Fu) | 0x64006400u;
  uint t1 = ((w >> 4) & 0x000F000Fu) | 0x64006400u;
  uint t2 = ((w >> 8) & 0x000F000Fu) | 0x64006400u;
  uint t3 = ((w >> 12) & 0x000F000Fu) | 0x64006400u;
  r.u[0] = __builtin_bit_cast(uint, (f16x2)((__builtin_bit_cast(f16x2, t0) - z) * s));
  r.u[1] = __builtin_bit_cast(uint, (f16x2)((__builtin_bit_cast(f16x2, t1) - z) * s));
  r.u[2] = __builtin_bit_cast(uint, (f16x2)((__builtin_bit_cast(f16x2, t2) - z) * s));
  r.u[3] = __builtin_bit_cast(uint, (f16x2)((__builtin_bit_cast(f16x2, t3) - z) * s));
  return r.v;
}

__device__ __forceinline__ uint dupf16(float x) {
  _Float16 h = (_Float16)x;
  unsigned short b = __builtin_bit_cast(unsigned short, h);
  return (uint)b * 0x00010001u;
}

// x [T,H] fp32 -> staged [T/128][H/8][128][8] f16, k-permuted within each 8:
// slot order = k0,k4,k1,k5,k2,k6,k3,k7 (matches dq8 output order)
__global__ void k_convert_x(const float* __restrict__ x, _Float16* __restrict__ xs) {
  const int kb = blockIdx.x;            // H/8 = 256
  const int mt = blockIdx.y;            // T/128 = 64
  const int m  = threadIdx.x;           // 128
  const float* src = x + (size_t)(mt * 128 + m) * HIDDEN + kb * 8;
  float4 f0 = *(const float4*)src;
  float4 f1 = *(const float4*)(src + 4);
  f16x8 v;
  v[0] = (_Float16)f0.x; v[1] = (_Float16)f1.x;
  v[2] = (_Float16)f0.y; v[3] = (_Float16)f1.y;
  v[4] = (_Float16)f0.z; v[5] = (_Float16)f1.z;
  v[6] = (_Float16)f0.w; v[7] = (_Float16)f1.w;
  *(f16x8*)(xs + ((size_t)(mt * 256 + kb) * 128 + m) * 8) = v;
}

// sz tables: per (group, n): dup-packed f16 scale and f16 (1025+z)
__global__ void k_prep_szgu(const uint* __restrict__ gz, const float* __restrict__ gs,
                            const uint* __restrict__ uz, const float* __restrict__ us,
                            uint4* __restrict__ out) {
  const int n = blockIdx.x * 256 + threadIdx.x;   // 5632 = 22*256
  const int g = blockIdx.y;                        // 16
  const int sh = (n & 7) * 4;
  int zg = (int)((gz[(size_t)g * (INTER / 8) + (n >> 3)] >> sh) & 0xFu);
  int zu = (int)((uz[(size_t)g * (INTER / 8) + (n >> 3)] >> sh) & 0xFu);
  float sg = gs[(size_t)g * INTER + n];
  float su = us[(size_t)g * INTER + n];
  out[(size_t)g * INTER + n] =
      make_uint4(dupf16(sg), dupf16((float)(1025 + zg)),
                 dupf16(su), dupf16((float)(1025 + zu)));
}

__global__ void k_prep_szd(const uint* __restrict__ dz, const float* __restrict__ ds,
                           uint2* __restrict__ out) {
  const int n = blockIdx.x * 256 + threadIdx.x;   // 2048 = 8*256
  const int g = blockIdx.y;                        // 44
  const int sh = (n & 7) * 4;
  int z = (int)((dz[(size_t)g * (HIDDEN / 8) + (n >> 3)] >> sh) & 0xFu);
  float s = ds[(size_t)g * HIDDEN + n];
  out[(size_t)g * HIDDEN + n] = make_uint2(dupf16(s), dupf16((float)(1025 + z)));
}

// GEMM1: h = silu(x@Wg) * (x@Wu); B = raw int4 qweight staged to LDS,
// dequanted in-register. tile 128x128, BK=64, 4 waves (2x2), 16x16x32 f16.
__global__ __launch_bounds__(256, 2)
void k_gemm_gateup(const _Float16* __restrict__ xs,
                   const uint* __restrict__ gq,
                   const uint* __restrict__ uq,
                   const uint4* __restrict__ szgu,
                   _Float16* __restrict__ hs) {
  __shared__ char smem[16384 + 4096 + 4096 + 2048];
  _Float16* Al = (_Float16*)smem;          // [8 kb][128 m][8] f16
  char* Bgl = smem + 16384;                // [8 kb][128 n] words (col^((kb&1)<<4))
  char* Bul = smem + 20480;
  char* szl = smem + 24576;                // [128 n][4 words]

  const int nt = blockIdx.x, mt = blockIdx.y;
  const int tid = threadIdx.x;
  const int wave = tid >> 6, lane = tid & 63;
  const int wm = wave >> 1, wn = wave & 1;
  const int row16 = lane >> 4, col = lane & 15;
  const int slot = wave * 4;

  const _Float16* gA = xs + (size_t)mt * 256 * 1024;

  // B staging: wave w stages 1KB chunk = qweight rows 2w,2w+1 of the kit
  const int brow = 2 * wave + (lane >> 5);
  const int bcolw = ((lane & 31) * 4) ^ ((brow & 1) << 4);   // bank swizzle
  const size_t bbase = (size_t)brow * INTER + nt * 128 + bcolw;

  int afo[4];
#pragma unroll
  for (int i = 0; i < 4; ++i)
    afo[i] = (row16 * 128 + wm * 64 + i * 16 + col) * 8;
  int bco[4];
  const int bswz = (row16 & 1) << 4;
#pragma unroll
  for (int ni = 0; ni < 4; ++ni)
    bco[ni] = (wn * 64 + ni * 16 + col) ^ bswz;

  const f32x4 zero = {0.f, 0.f, 0.f, 0.f};
  f32x4 accg[4][4], accu[4][4];
#pragma unroll
  for (int i = 0; i < 4; ++i)
#pragma unroll
    for (int j = 0; j < 4; ++j) { accg[i][j] = zero; accu[i][j] = zero; }

  uint2 szg[4], szu[4];

  for (int kit = 0; kit < HIDDEN / 64; ++kit) {        // 32 iters
    __syncthreads();
#pragma unroll
    for (int q = 0; q < 4; ++q) {
      const int c2 = (slot + q) * 64 + lane;
      async_copy16(gA + (size_t)kit * 8192 + (size_t)c2 * 8,
                   (char*)Al + (slot + q) * 1024);
    }
    {
      const size_t go = (size_t)kit * 8 * INTER + bbase;
      async_copy16(gq + go, Bgl + wave * 1024);
      async_copy16(uq + go, Bul + wave * 1024);
    }
    if (((kit & 1) == 0) && wave < 2) {
      const int n = wave * 64 + lane;
      async_copy16(szgu + (size_t)(kit >> 1) * INTER + nt * 128 + n,
                   szl + wave * 1024);
    }
    __syncthreads();
    if ((kit & 1) == 0) {
#pragma unroll
      for (int ni = 0; ni < 4; ++ni) {
        const int n16 = (wn * 64 + ni * 16 + col) * 16;
        szg[ni] = *(const uint2*)(szl + n16);
        szu[ni] = *(const uint2*)(szl + n16 + 8);
      }
    }
#pragma unroll
    for (int ks = 0; ks < 2; ++ks) {
      const int kadd = ks * 4096;
      f16x8 af[4];
#pragma unroll
      for (int i = 0; i < 4; ++i)
        af[i] = *(const f16x8*)(Al + kadd + afo[i]);
      const int bks = (ks * 4 + row16) * 512;          // byte row base
      uint bgw[4], buw[4];
#pragma unroll
      for (int ni = 0; ni < 4; ++ni) {
        bgw[ni] = *(const uint*)(Bgl + bks + bco[ni] * 4);
        buw[ni] = *(const uint*)(Bul + bks + bco[ni] * 4);
      }
      f16x8 bgf[4], buf_[4];
#pragma unroll
      for (int ni = 0; ni < 4; ++ni) {
        bgf[ni] = dq8(bgw[ni], szg[ni].x, szg[ni].y);
        buf_[ni] = dq8(buw[ni], szu[ni].x, szu[ni].y);
      }
#pragma unroll
      for (int mi = 0; mi < 4; ++mi)
#pragma unroll
        for (int ni = 0; ni < 4; ++ni) {
          accg[mi][ni] = __builtin_amdgcn_mfma_f32_16x16x32_f16(af[mi], bgf[ni], accg[mi][ni], 0, 0, 0);
          accu[mi][ni] = __builtin_amdgcn_mfma_f32_16x16x32_f16(af[mi], buf_[ni], accu[mi][ni], 0, 0, 0);
        }
    }
  }
  // epilogue: h = silu(g)*u -> hs staged [T/128][I/8][128][slot], k-permuted
#pragma unroll
  for (int mi = 0; mi < 4; ++mi)
#pragma unroll
    for (int ni = 0; ni < 4; ++ni) {
      const int kg = nt * 128 + wn * 64 + ni * 16 + col;
      const int sub = kg & 7;
      const int pslot = ((sub & 3) << 1) | (sub >> 2);   // P^-1
      const size_t base = (size_t)(mt * (INTER / 8) + (kg >> 3)) * 1024 + pslot;
#pragma unroll
      for (int r = 0; r < 4; ++r) {
        float g = accg[mi][ni][r], u = accu[mi][ni][r];
        float h = g / (1.f + __expf(-g)) * u;
        const int ml = wm * 64 + mi * 16 + row16 * 4 + r;
        hs[base + (size_t)ml * 8] = (_Float16)h;
      }
    }
}

// GEMM2: out = h @ Wd (int4 staged + in-register dequant), fp32 out [T, H]
__global__ __launch_bounds__(256, 2)
void k_gemm_down(const _Float16* __restrict__ hs,
                 const uint* __restrict__ dq,
                 const uint2* __restrict__ szd,
                 float* __restrict__ out) {
  __shared__ char smem[16384 + 4096 + 1024];
  _Float16* Al = (_Float16*)smem;
  char* Bl  = smem + 16384;
  char* szl = smem + 20480;                // [128 n][2 words]

  const int nt = blockIdx.x, mt = blockIdx.y;
  const int tid = threadIdx.x;
  const int wave = tid >> 6, lane = tid & 63;
  const int wm = wave >> 1, wn = wave & 1;
  const int row16 = lane >> 4, col = lane & 15;
  const int slot = wave * 4;

  const _Float16* gA = hs + (size_t)mt * (INTER / 8) * 1024;

  const int brow = 2 * wave + (lane >> 5);
  const int bcolw = ((lane & 31) * 4) ^ ((brow & 1) << 4);
  const size_t bbase = (size_t)brow * HIDDEN + nt * 128 + bcolw;

  int afo[4];
#pragma unroll
  for (int i = 0; i < 4; ++i)
    afo[i] = (row16 * 128 + wm * 64 + i * 16 + col) * 8;
  int bco[4];
  const int bswz = (row16 & 1) << 4;
#pragma unroll
  for (int ni = 0; ni < 4; ++ni)
    bco[ni] = (wn * 64 + ni * 16 + col) ^ bswz;

  const f32x4 zero = {0.f, 0.f, 0.f, 0.f};
  f32x4 acc[4][4];
#pragma unroll
  for (int i = 0; i < 4; ++i)
#pragma unroll
    for (int j = 0; j < 4; ++j) acc[i][j] = zero;

  uint2 sz[4];

  for (int kit = 0; kit < INTER / 64; ++kit) {          // 88 iters
    __syncthreads();
#pragma unroll
    for (int q = 0; q < 4; ++q) {
      const int c2 = (slot + q) * 64 + lane;
      async_copy16(gA + (size_t)kit * 8192 + (size_t)c2 * 8,
                   (char*)Al + (slot + q) * 1024);
    }
    async_copy16(dq + (size_t)kit * 8 * HIDDEN + bbase, Bl + wave * 1024);
    if (((kit & 1) == 0) && wave == 0) {
      async_copy16(szd + (size_t)(kit >> 1) * HIDDEN + nt * 128 + lane * 2, szl);
    }
    __syncthreads();
    if ((kit & 1) == 0) {
#pragma unroll
      for (int ni = 0; ni < 4; ++ni) {
        const int n8 = (wn * 64 + ni * 16 + col) * 8;
        sz[ni] = *(const uint2*)(szl + n8);
      }
    }
#pragma unroll
    for (int ks = 0; ks < 2; ++ks) {
      const int kadd = ks * 4096;
      f16x8 af[4];
#pragma unroll
      for (int i = 0; i < 4; ++i)
        af[i] = *(const f16x8*)(Al + kadd + afo[i]);
      const int bks = (ks * 4 + row16) * 512;
      uint bw[4];
#pragma unroll
      for (int ni = 0; ni < 4; ++ni)
        bw[ni] = *(const uint*)(Bl + bks + bco[ni] * 4);
      f16x8 bf[4];
#pragma unroll
      for (int ni = 0; ni < 4; ++ni)
        bf[ni] = dq8(bw[ni], sz[ni].x, sz[ni].y);
#pragma unroll
      for (int mi = 0; mi < 4; ++mi)
#pragma unroll
        for (int ni = 0; ni < 4; ++ni)
          acc[mi][ni] = __builtin_amdgcn_mfma_f32_16x16x32_f16(af[mi], bf[ni], acc[mi][ni], 0, 0, 0);
    }
  }
#pragma unroll
  for (int mi = 0; mi < 4; ++mi)
#pragma unroll
    for (int ni = 0; ni < 4; ++ni) {
      const int n = nt * 128 + wn * 64 + ni * 16 + col;
#pragma unroll
      for (int r = 0; r < 4; ++r) {
        const int m = mt * 128 + wm * 64 + mi * 16 + row16 * 4 + r;
        out[(size_t)m * HIDDEN + n] = acc[mi][ni][r];
      }
    }
}

extern "C" void kernel_launch(void* const* d_in, const int* in_sizes, int n_in,
                              void* d_out, int out_size, void* d_ws, size_t ws_size,
                              hipStream_t stream) {
  (void)in_sizes; (void)n_in; (void)out_size; (void)ws_size;
  const float* x  = (const float*)d_in[0];
  const uint*  gq = (const uint*)d_in[1];
  const uint*  gz = (const uint*)d_in[2];
  const float* gs = (const float*)d_in[3];
  const uint*  uq = (const uint*)d_in[4];
  const uint*  uz = (const uint*)d_in[5];
  const float* us = (const float*)d_in[6];
  const uint*  dq = (const uint*)d_in[7];
  const uint*  dz = (const uint*)d_in[8];
  const float* ds = (const float*)d_in[9];
  float* out = (float*)d_out;

  // ws: xs 32MB | hs 92.3MB | szgu 1.44MB | szd 0.72MB  (~126MB total)
  char* ws = (char*)d_ws;
  _Float16* xs  = (_Float16*)ws;
  _Float16* hs  = (_Float16*)(ws + (size_t)TOKENS * HIDDEN * 2);
  uint4* szgu = (uint4*)(ws + (size_t)TOKENS * HIDDEN * 2 + (size_t)TOKENS * INTER * 2);
  uint2* szd  = (uint2*)((char*)szgu + (size_t)16 * INTER * 16);

  k_convert_x<<<dim3(HIDDEN / 8, TOKENS / 128), 128, 0, stream>>>(x, xs);
  k_prep_szgu<<<dim3(INTER / 256, HIDDEN / 128), 256, 0, stream>>>(gz, gs, uz, us, szgu);
  k_prep_szd<<<dim3(HIDDEN / 256, INTER / 128), 256, 0, stream>>>(dz, ds, szd);
  k_gemm_gateup<<<dim3(INTER / 128, TOKENS / 128), 256, 0, stream>>>(xs, gq, uq, szgu, hs);
  k_gemm_down<<<dim3(HIDDEN / 128, TOKENS / 128), 256, 0, stream>>>(hs, dq, szd, out);
}